// Round 5
// baseline (94.862 us; speedup 1.0000x reference)
//
#include <hip/hip_runtime.h>

// Fused grouped 1x1 conv (q,k,v) + 5x5 reflect-window per-channel softmax attention.
// x: (2,128,96,96) f32; wq/wk/wv: (4,32,32) f32; out: (2,128,96,96) f32.
// Block = (8x8 tile, group, batch), 256 thr = 4 waves; wave owns 8 out-channels.
//
// R5: phase-3 critical path attacked:
//  - exp via __builtin_amdgcn_exp2f (schedulable; the R3/R4 inline asm blocked
//    software pipelining of the 200-tap stream).
//  - kv packed [pos][ch] (stride 33 dwords, 2-way max banking): channel PAIRS
//    read adjacent dwords -> ds_read2_b32 serves 2 channels, chains interleave.
//  - row-partial den/num accumulators: 5-deep chains instead of 25-deep.
// LDS 32320 B -> 5 blocks/CU; grid 1152 fully resident.

#define HW 96
#define RG 12
#define NPOS 144
#define CSTR 33            // dwords per position row in kvb (32 ch + 1 pad)

typedef short short8 __attribute__((ext_vector_type(8)));
typedef float float4v __attribute__((ext_vector_type(4)));

#if __has_builtin(__builtin_amdgcn_exp2f)
#define EXP2(x) __builtin_amdgcn_exp2f(x)
#else
#define EXP2(x) __expf((x) * 0.6931471805599453f)
#endif

__device__ __forceinline__ int refl(int i) {
    i = (i < 0) ? -i : i;          // reflect (edge excluded): -1->1, -2->2
    i = (i > 95) ? (190 - i) : i;  // 96->94, 97->93
    return i;
}

// float -> bf16 bits, round-to-nearest (no tie-to-even; inputs are tame)
__device__ __forceinline__ unsigned int bfr(float f) {
    return (__float_as_uint(f) + 0x8000u) >> 16;
}

__global__ __launch_bounds__(256) void fused_attn(
    const float* __restrict__ x, const float* __restrict__ wq,
    const float* __restrict__ wk, const float* __restrict__ wv,
    float* __restrict__ out)
{
    __shared__ unsigned short xs[NPOS * 32];     // bf16 x, [pos][cin]        9216 B
    __shared__ unsigned int   kvb[NPOS * CSTR];  // k(lo16)|v(hi16) [pos][ch] 19008 B
    __shared__ unsigned short qs[32 * 64];       // bf16 q, [ch][pixel]       4096 B

    const int tid = threadIdx.x;
    const int g = blockIdx.y, b = blockIdx.z;
    const int h0 = (blockIdx.x / 12) * 8;
    const int w0 = (blockIdx.x % 12) * 8;
    const float* xg = x + (size_t)(b * 128 + g * 32) * (HW * HW);

    // ---- Phase 1: coalesced staging (aligned float4 row loads; 16 cols cover 12) ----
    const int wA   = min(max(w0 - 4, 0), 80);
    const int colB = wA - w0 + 2;                // region col of first loaded float
    #pragma unroll
    for (int it = 0; it < 6; it++) {
        int idx = it * 256 + tid;                // 1536 = 32ch x 12row x 4seg
        int seg = idx & 3;
        int pr  = idx >> 2;
        int ch  = pr & 31;
        int row = pr >> 5;
        int iy  = refl(h0 + row - 2);
        const float4v f4 = *(const float4v*)(xg + ch * (HW * HW) + iy * HW + wA + seg * 4);
        int col0 = colB + seg * 4;
        #pragma unroll
        for (int e = 0; e < 4; e++) {
            int col = col0 + e;
            if (col >= 0 && col < RG)
                xs[(row * RG + col) * 32 + ch] = (unsigned short)bfr(f4[e]);
        }
    }

    // ---- Weight B-fragments (global loads in flight across the barrier) ----
    const int wid  = tid >> 6;
    const int lane = tid & 63;
    const int n0   = wid * 8;          // this wave's channel base
    const int col  = lane & 15;        // MFMA n / m index
    const int quad = lane >> 4;        // 0..3
    const int koff = quad * 8;         // K offset of this lane's 8 bf16

    const float* wrow = (col < 8) ? (wk + (g * 32 + n0 + col) * 32)
                                  : (wv + (g * 32 + n0 + col - 8) * 32);
    short8 bkv;
    #pragma unroll
    for (int j = 0; j < 8; j++)
        ((unsigned short*)&bkv)[j] = (unsigned short)bfr(wrow[koff + j]);

    short8 bq = {0, 0, 0, 0, 0, 0, 0, 0};   // cols 8-15 zero
    if (col < 8) {
        const float* qr = wq + (g * 32 + n0 + col) * 32;
        #pragma unroll
        for (int j = 0; j < 8; j++)
            ((unsigned short*)&bq)[j] = (unsigned short)bfr(qr[koff + j]);
    }

    // ---- Reflect halo columns for edge tiles (in-LDS copy) ----
    if (w0 == 0 || w0 == 88) {
        __syncthreads();                         // staging writes visible
        const int left = (w0 == 0);
        for (int it = 0; it < 3; it++) {
            int idx = it * 256 + tid;            // 768 = 32ch x 12row x 2cols
            int ch  = idx & 31;
            int rr  = idx >> 5;                  // 0..23
            int row = rr >> 1, wc = rr & 1;
            int dstc = left ? wc : (10 + wc);      // L: {0,1}  R: {10,11}
            int srcc = left ? (4 - wc) : (8 - wc); // L: {4,3} R: {8,7}
            xs[(row * RG + dstc) * 32 + ch] = xs[(row * RG + srcc) * 32 + ch];
        }
    }
    __syncthreads();

    // ---- Phase 2a: k,v conv — 9 MFMAs cover 144 positions x 16 (k8+v8) ----
    unsigned short* kv16 = (unsigned short*)kvb;
    #pragma unroll
    for (int t = 0; t < 9; t++) {
        int pa = t * 16 + col;                      // A row m -> region pos
        short8 a = *(const short8*)&xs[pa * 32 + koff];
        float4v d = {0.f, 0.f, 0.f, 0.f};
        d = __builtin_amdgcn_mfma_f32_16x16x32_bf16(a, bkv, d, 0, 0, 0);
        // D: col = ch/type (n), rows quad*4+r = pos within tile-of-16
        int c    = n0 + (col & 7);
        int half = col >> 3;                        // k -> lo16, v -> hi16
        #pragma unroll
        for (int r = 0; r < 4; r++) {
            int p = t * 16 + quad * 4 + r;
            kv16[(p * CSTR + c) * 2 + half] = (unsigned short)bfr(d[r]);
        }
    }

    // ---- Phase 2b: q conv — 4 MFMAs over the 64 center pixels ----
    #pragma unroll
    for (int t = 0; t < 4; t++) {
        int mp = t * 16 + col;                      // center pixel id 0..63
        int p  = ((mp >> 3) + 2) * RG + (mp & 7) + 2;
        short8 a = *(const short8*)&xs[p * 32 + koff];
        float4v d = {0.f, 0.f, 0.f, 0.f};
        d = __builtin_amdgcn_mfma_f32_16x16x32_bf16(a, bq, d, 0, 0, 0);
        if (col < 8) {
            unsigned int* dst = (unsigned int*)&qs[(n0 + col) * 64 + t * 16 + quad * 4];
            unsigned int u0 = __float_as_uint(d[0]) + 0x8000u;
            unsigned int u1 = __float_as_uint(d[1]) + 0x8000u;
            unsigned int u2 = __float_as_uint(d[2]) + 0x8000u;
            unsigned int u3 = __float_as_uint(d[3]) + 0x8000u;
            dst[0] = __builtin_amdgcn_perm(u1, u0, 0x07060302); // hi16|hi16<<16
            dst[1] = __builtin_amdgcn_perm(u3, u2, 0x07060302);
        }
    }

    __syncthreads();

    // ---- Phase 3: 25-tap softmax, channel PAIRS; lane = pixel ----
    const int ty = lane >> 3, tx = lane & 7;
    float* outp = out + (size_t)((b * 128 + g * 32 + n0) * HW + (h0 + ty)) * HW + (w0 + tx);
    for (int j = 0; j < 4; j++) {
        int c0 = n0 + 2 * j;
        float q0 = __uint_as_float((unsigned int)qs[c0 * 64 + lane] << 16) * 1.44269504f;
        float q1 = __uint_as_float((unsigned int)qs[(c0 + 1) * 64 + lane] << 16) * 1.44269504f;
        float den0 = 0.f, num0 = 0.f, den1 = 0.f, num1 = 0.f;
        #pragma unroll
        for (int dy = 0; dy < 5; dy++) {
            const unsigned int* rowp = &kvb[((ty + dy) * RG + tx) * CSTR + c0];
            float rd0 = 0.f, rn0 = 0.f, rd1 = 0.f, rn1 = 0.f;
            #pragma unroll
            for (int dx = 0; dx < 5; dx++) {
                unsigned int u0 = rowp[dx * CSTR];
                unsigned int u1 = rowp[dx * CSTR + 1];
                float k0 = __uint_as_float(u0 << 16);
                float v0 = __uint_as_float(u0 & 0xffff0000u);
                float k1 = __uint_as_float(u1 << 16);
                float v1 = __uint_as_float(u1 & 0xffff0000u);
                float e0 = EXP2(q0 * k0);
                float e1 = EXP2(q1 * k1);
                rd0 += e0; rn0 = fmaf(e0, v0, rn0);
                rd1 += e1; rn1 = fmaf(e1, v1, rn1);
            }
            den0 += rd0; num0 += rn0; den1 += rd1; num1 += rn1;
        }
        outp[(2 * j)     * (HW * HW)] = num0 * __builtin_amdgcn_rcpf(den0);
        outp[(2 * j + 1) * (HW * HW)] = num1 * __builtin_amdgcn_rcpf(den1);
    }
}

extern "C" void kernel_launch(void* const* d_in, const int* in_sizes, int n_in,
                              void* d_out, int out_size, void* d_ws, size_t ws_size,
                              hipStream_t stream) {
    const float* x  = (const float*)d_in[0];
    const float* wq = (const float*)d_in[1];
    const float* wk = (const float*)d_in[2];
    const float* wv = (const float*)d_in[3];
    float* out = (float*)d_out;

    dim3 grid(144, 4, 2);   // (spatial tiles, groups, batch)
    fused_attn<<<grid, 256, 0, stream>>>(x, wq, wk, wv, out);
}

// Round 6
// 91.766 us; speedup vs baseline: 1.0337x; 1.0337x over previous
//
#include <hip/hip_runtime.h>

// Fused grouped 1x1 conv (q,k,v) + 5x5 reflect-window per-channel softmax attention.
// x: (2,128,96,96) f32; wq/wk/wv: (4,32,32) f32; out: (2,128,96,96) f32.
// Block = (8x8 tile, group, batch), 256 thr = 4 waves; wave owns 8 out-channels.
//
// R6: f16 data path (mfma_f32_16x16x32_f16; more mantissa than bf16, no unpack
//     shifts -> v_cvt_f32_f16 / v_fma_mix). kv rows 16B-aligned (CSTR=36):
//     8ch/tap = 2 ds_read_b128 (R5's CSTR=33 degraded to scalar b32s).
//     Full 8-ch tap loop, row-wise load-then-compute (10 b128 in flight).
//     wq pre-scaled by log2e. q stored [px][ch] -> 1 b128/lane. qs aliases
//     dead xs -> LDS 29952 B, 5 blocks/CU.

#define HW 96
#define RG 12
#define NPOS 144
#define CSTR 36            // dwords per position row in kvb (32 ch + 4 pad; 144B = 16B-aligned)

typedef _Float16 half8  __attribute__((ext_vector_type(8)));
typedef _Float16 half2v __attribute__((ext_vector_type(2)));
typedef float    float4v __attribute__((ext_vector_type(4)));
typedef unsigned int uint4v __attribute__((ext_vector_type(4)));

__device__ __forceinline__ int refl(int i) {
    i = (i < 0) ? -i : i;          // reflect (edge excluded): -1->1, -2->2
    i = (i > 95) ? (190 - i) : i;  // 96->94, 97->93
    return i;
}

__global__ __launch_bounds__(256) void fused_attn(
    const float* __restrict__ x, const float* __restrict__ wq,
    const float* __restrict__ wk, const float* __restrict__ wv,
    float* __restrict__ out)
{
    // xs: f16 [144 pos][32 ch] = 9216 B (dead after phase 2; qs aliases it)
    // kvb: [144 pos][36 dwords] (k lo16 | v hi16 per ch, 32 used) = 20736 B
    __shared__ alignas(16) unsigned char smem[9216 + 20736];
    _Float16*     xs  = (_Float16*)smem;
    unsigned int* kvb = (unsigned int*)(smem + 9216);
    _Float16*     qs  = (_Float16*)smem;        // alias: [64 px][32 ch] f16, 4 KB

    const int tid = threadIdx.x;
    const int g = blockIdx.y, b = blockIdx.z;
    const int h0 = (blockIdx.x / 12) * 8;
    const int w0 = (blockIdx.x % 12) * 8;
    const float* xg = x + (size_t)(b * 128 + g * 32) * (HW * HW);

    // ---- Phase 1: coalesced staging (aligned float4 row loads; 16 cols cover 12) ----
    const int wA   = min(max(w0 - 4, 0), 80);
    const int colB = wA - w0 + 2;                // region col of first loaded float
    #pragma unroll
    for (int it = 0; it < 6; it++) {
        int idx = it * 256 + tid;                // 1536 = 32ch x 12row x 4seg
        int seg = idx & 3;
        int pr  = idx >> 2;
        int ch  = pr & 31;
        int row = pr >> 5;
        int iy  = refl(h0 + row - 2);
        const float4v f4 = *(const float4v*)(xg + ch * (HW * HW) + iy * HW + wA + seg * 4);
        int col0 = colB + seg * 4;
        #pragma unroll
        for (int e = 0; e < 4; e++) {
            int col = col0 + e;
            if (col >= 0 && col < RG)
                xs[(row * RG + col) * 32 + ch] = (_Float16)f4[e];
        }
    }

    // ---- Weight B-fragments (global loads in flight across the barrier) ----
    const int wid  = tid >> 6;
    const int lane = tid & 63;
    const int n0   = wid * 8;          // this wave's channel base
    const int col  = lane & 15;        // MFMA n / m index
    const int quad = lane >> 4;        // 0..3
    const int koff = quad * 8;         // K offset of this lane's 8 f16

    const float* wrow = (col < 8) ? (wk + (g * 32 + n0 + col) * 32)
                                  : (wv + (g * 32 + n0 + col - 8) * 32);
    half8 bkv;
    #pragma unroll
    for (int j = 0; j < 8; j++)
        bkv[j] = (_Float16)wrow[koff + j];

    half8 bq = {0, 0, 0, 0, 0, 0, 0, 0};   // cols 8-15 zero
    if (col < 8) {
        const float* qr = wq + (g * 32 + n0 + col) * 32;
        #pragma unroll
        for (int j = 0; j < 8; j++)
            bq[j] = (_Float16)(qr[koff + j] * 1.44269504f);  // fold log2(e) into wq
    }

    // ---- Reflect halo columns for edge tiles (in-LDS copy) ----
    if (w0 == 0 || w0 == 88) {
        __syncthreads();                         // staging writes visible
        const int left = (w0 == 0);
        for (int it = 0; it < 3; it++) {
            int idx = it * 256 + tid;            // 768 = 32ch x 12row x 2cols
            int ch  = idx & 31;
            int rr  = idx >> 5;                  // 0..23
            int row = rr >> 1, wc = rr & 1;
            int dstc = left ? wc : (10 + wc);      // L: {0,1}  R: {10,11}
            int srcc = left ? (4 - wc) : (8 - wc); // L: {4,3} R: {8,7}
            xs[(row * RG + dstc) * 32 + ch] = xs[(row * RG + srcc) * 32 + ch];
        }
    }
    __syncthreads();

    // ---- Phase 2a: k,v conv — 9 MFMAs cover 144 positions x 16 (k8+v8) ----
    _Float16* kv16 = (_Float16*)kvb;
    #pragma unroll
    for (int t = 0; t < 9; t++) {
        int pa = t * 16 + col;                      // A row m -> region pos
        half8 a = *(const half8*)&xs[pa * 32 + koff];
        float4v d = {0.f, 0.f, 0.f, 0.f};
        d = __builtin_amdgcn_mfma_f32_16x16x32_f16(a, bkv, d, 0, 0, 0);
        // D: col = ch/type (n), rows quad*4+r = pos within tile-of-16
        int c    = n0 + (col & 7);
        int half_ = col >> 3;                       // k -> lo16, v -> hi16
        #pragma unroll
        for (int r = 0; r < 4; r++) {
            int p = t * 16 + quad * 4 + r;
            kv16[(p * CSTR + c) * 2 + half_] = (_Float16)d[r];
        }
    }

    // ---- Phase 2b: q conv — 4 MFMAs over the 64 center pixels (results in regs) ----
    float4v dqv[4];
    #pragma unroll
    for (int t = 0; t < 4; t++) {
        int mp = t * 16 + col;                      // center pixel id 0..63
        int p  = ((mp >> 3) + 2) * RG + (mp & 7) + 2;
        half8 a = *(const half8*)&xs[p * 32 + koff];
        float4v z = {0.f, 0.f, 0.f, 0.f};
        dqv[t] = __builtin_amdgcn_mfma_f32_16x16x32_f16(a, bq, z, 0, 0, 0);
    }

    __syncthreads();   // all xs reads done -> safe to overwrite with qs

    if (col < 8) {
        #pragma unroll
        for (int t = 0; t < 4; t++) {
            #pragma unroll
            for (int r = 0; r < 4; r++) {
                int pix = t * 16 + quad * 4 + r;
                qs[pix * 32 + n0 + col] = (_Float16)dqv[t][r];
            }
        }
    }
    __syncthreads();

    // ---- Phase 3: 25-tap softmax, all 8 channels; lane = pixel ----
    const int ty = lane >> 3, tx = lane & 7;

    half8 qh = *(const half8*)&qs[lane * 32 + n0];  // 1 ds_read_b128
    float qf[8];
    #pragma unroll
    for (int c = 0; c < 8; c++) qf[c] = (float)qh[c];   // pre-scaled by log2e

    float den[8], num[8];
    #pragma unroll
    for (int c = 0; c < 8; c++) { den[c] = 0.f; num[c] = 0.f; }

    #pragma unroll
    for (int dy = 0; dy < 5; dy++) {
        const unsigned int* base = &kvb[((ty + dy) * RG + tx) * CSTR + n0];
        uint4v t0[5], t1[5];
        #pragma unroll
        for (int dx = 0; dx < 5; dx++) {            // 10 ds_read_b128 batched
            t0[dx] = *(const uint4v*)(base + dx * CSTR);
            t1[dx] = *(const uint4v*)(base + dx * CSTR + 4);
        }
        #pragma unroll
        for (int dx = 0; dx < 5; dx++) {
            #pragma unroll
            for (int c = 0; c < 8; c++) {
                unsigned int u = (c < 4) ? t0[dx][c] : t1[dx][c - 4];
                half2v kv = __builtin_bit_cast(half2v, u);
                float e = __builtin_amdgcn_exp2f(qf[c] * (float)kv[0]);
                den[c] += e;
                num[c] = fmaf(e, (float)kv[1], num[c]);
            }
        }
    }

    float* outp = out + (size_t)((b * 128 + g * 32 + n0) * HW + (h0 + ty)) * HW + (w0 + tx);
    #pragma unroll
    for (int c = 0; c < 8; c++)
        outp[c * (HW * HW)] = num[c] * __builtin_amdgcn_rcpf(den[c]);
}

extern "C" void kernel_launch(void* const* d_in, const int* in_sizes, int n_in,
                              void* d_out, int out_size, void* d_ws, size_t ws_size,
                              hipStream_t stream) {
    const float* x  = (const float*)d_in[0];
    const float* wq = (const float*)d_in[1];
    const float* wk = (const float*)d_in[2];
    const float* wv = (const float*)d_in[3];
    float* out = (float*)d_out;

    dim3 grid(144, 4, 2);   // (spatial tiles, groups, batch)
    fused_attn<<<grid, 256, 0, stream>>>(x, wq, wk, wv, out);
}